// Round 1
// baseline (310.565 us; speedup 1.0000x reference)
//
#include <hip/hip_runtime.h>

#define NN 50000
#define NE 800000
#define D  128

typedef _Float16 f16;
typedef _Float16 f16x4 __attribute__((ext_vector_type(4)));
typedef _Float16 f16x8 __attribute__((ext_vector_type(8)));
typedef float f32x4 __attribute__((ext_vector_type(4)));
typedef float f32x2 __attribute__((ext_vector_type(2)));
typedef unsigned short u16;
typedef unsigned int u32;
typedef unsigned char u8;

// ---------------- prep: f32->f16 + f32->fp8 converts + deg zeroing ----------------
// blocks [0,6250): x -> xf (f16) and xf8 (fp8); [6250,6346): 6 weight mats; rest: zero deg
__global__ __launch_bounds__(256) void prep(
    const float* __restrict__ x, f16* __restrict__ xf, u8* __restrict__ xf8,
    const float* w0, const float* w1, const float* w2,
    const float* w3, const float* w4, const float* w5,
    f16* d0, f16* d1, f16* d2, f16* d3, f16* d4, f16* d5,
    int* __restrict__ deg) {
    int b = blockIdx.x;
    if (b < 6250) {
        int i = b * 256 + threadIdx.x;
        float4 v = ((const float4*)x)[i];
        f16x4 o = {(f16)v.x, (f16)v.y, (f16)v.z, (f16)v.w};
        ((f16x4*)xf)[i] = o;
        u32 lo = __builtin_amdgcn_cvt_pk_fp8_f32(v.x, v.y, 0, false);
        u32 pk = __builtin_amdgcn_cvt_pk_fp8_f32(v.z, v.w, lo, true);
        ((u32*)xf8)[i] = pk;
    } else if (b < 6346) {
        int wb = b - 6250;
        int mat = wb >> 4;
        const float* s; f16* d;
        switch (mat) {
            case 0: s = w0; d = d0; break; case 1: s = w1; d = d1; break;
            case 2: s = w2; d = d2; break; case 3: s = w3; d = d3; break;
            case 4: s = w4; d = d4; break; default: s = w5; d = d5; break;
        }
        int i = (wb & 15) * 256 + threadIdx.x;   // 0..4095 float4
        float4 v = ((const float4*)s)[i];
        f16x4 o = {(f16)v.x, (f16)v.y, (f16)v.z, (f16)v.w};
        ((f16x4*)d)[i] = o;
    } else {
        int i = (b - 6346) * 256 + threadIdx.x;
        if (i < NN) deg[i] = 0;
    }
}

// ---------------- CSR build ----------------

__global__ __launch_bounds__(256) void count_deg_rank(
    const int* __restrict__ row, int* __restrict__ deg, u16* __restrict__ rank, int e) {
    int i = blockIdx.x * blockDim.x + threadIdx.x;
    if (i < e) rank[i] = (u16)atomicAdd(&deg[row[i]], 1);
}

__global__ void scan_partial(const int* __restrict__ deg, int* __restrict__ bsum, int n) {
    __shared__ int s[1024];
    int i = blockIdx.x * 1024 + threadIdx.x;
    s[threadIdx.x] = (i < n) ? deg[i] : 0;
    __syncthreads();
    for (int off = 512; off > 0; off >>= 1) {
        if (threadIdx.x < off) s[threadIdx.x] += s[threadIdx.x + off];
        __syncthreads();
    }
    if (threadIdx.x == 0) bsum[blockIdx.x] = s[0];
}

// final scan with inline exclusive block-prefix (wave-reduce over bsum)
__global__ void scan_final(const int* __restrict__ deg, const int* __restrict__ bsum,
                           int* __restrict__ offsets, int n, int nb) {
    __shared__ int s[1024];
    __shared__ int base;
    if (threadIdx.x < 64) {
        int t = threadIdx.x;
        int v = (t < nb && t < (int)blockIdx.x) ? bsum[t] : 0;
#pragma unroll
        for (int m = 1; m < 64; m <<= 1) v += __shfl_xor(v, m, 64);
        if (t == 0) base = v;
    }
    int i = blockIdx.x * 1024 + threadIdx.x;
    int dv = (i < n) ? deg[i] : 0;
    s[threadIdx.x] = dv;
    __syncthreads();
    for (int off = 1; off < 1024; off <<= 1) {
        int t = (threadIdx.x >= (unsigned)off) ? s[threadIdx.x - off] : 0;
        __syncthreads();
        s[threadIdx.x] += t;
        __syncthreads();
    }
    if (i < n) {
        offsets[i + 1] = s[threadIdx.x] + base;
        if (i == 0) offsets[0] = 0;
    }
}

__global__ __launch_bounds__(256) void fill_csr(
    const int* __restrict__ row, const int* __restrict__ col,
    const u16* __restrict__ rank, const int* __restrict__ offsets,
    u16* __restrict__ csr_col, int e) {
    int i = blockIdx.x * blockDim.x + threadIdx.x;
    if (i < e) {
        int p = offsets[row[i]] + (int)rank[i];
        csr_col[p] = (u16)col[i];
    }
}

// ---------------- fused aggregate + MFMA dual-GEMM ----------------
// Aggregation happens directly into the MFMA A-fragment registers:
// lane (lm,q) of a wave owns row mt+lm, features {ks*32+q*8 .. +8} (ks=0..3).
// The 4 q-lanes of one row together fetch the full 128B fp8 row per edge
// (4 x uint2 each, 32B-coalesced runs), accumulate f32, scale by 1/deg,
// convert to f16 fragments. No LDS staging of agg, no aggb buffer.
//
// out[m][n] = agg[m][k]*Wl[n][k] + relu?(x[m][k])*Wr[n][k] + b[n] (+ x[m][n])
// When !OUT_F32 also writes out8 = fp8(relu(out)) for the NEXT layer's gather.
// NOTE: out8 must be a DIFFERENT buffer than h8 (gathers race with epilogue
// writes across blocks) -> fp8 buffers ping-pong between layers.
#define WPAD 72   // 64 + 8 f16 pad -> 144B row stride, <=2-way bank aliasing

template<int RELU_X, int ADD_RES, int OUT_F32>
__global__ __launch_bounds__(256, 4) void sage_fused_mfma(
    const u8* __restrict__ h8, const int* __restrict__ offsets,
    const u16* __restrict__ csr, const f16* __restrict__ xb,
    const f16* __restrict__ Wl, const f16* __restrict__ Wr,
    const float* __restrict__ bias, float* __restrict__ outf,
    f16* __restrict__ outh, u8* __restrict__ out8) {
    __shared__ f16 sW[2][128][WPAD];   // 36864 B

    const int tid  = threadIdx.x;
    const int wave = tid >> 6;
    const int lane = tid & 63;
    const int lm = lane & 15;
    const int q  = lane >> 4;
    const int mt = blockIdx.x * 64 + wave * 16;

    int row = mt + lm;
    int rclamp = (row < NN) ? row : NN - 1;

    // ---- phase 1: aggregate fp8 neighbors into A-fragment accumulators ----
    int s0  = offsets[rclamp];
    int deg = offsets[rclamp + 1] - s0;

    float acc_agg[4][8];
#pragma unroll
    for (int ks = 0; ks < 4; ++ks)
#pragma unroll
        for (int u = 0; u < 8; ++u) acc_agg[ks][u] = 0.f;

    // wave-uniform trip count = max deg over the 16 rows (q-lanes share deg)
    int dmax = deg;
#pragma unroll
    for (int m = 1; m < 16; m <<= 1) {
        int o = __shfl_xor(dmax, m, 64);
        dmax = (o > dmax) ? o : dmax;
    }

#define UNPACK_ADD(ks, w)                                              \
    do {                                                               \
        f32x2 p;                                                       \
        p = __builtin_amdgcn_cvt_pk_f32_fp8((w).x, false);             \
        acc_agg[ks][0] += p.x; acc_agg[ks][1] += p.y;                  \
        p = __builtin_amdgcn_cvt_pk_f32_fp8((w).x, true);              \
        acc_agg[ks][2] += p.x; acc_agg[ks][3] += p.y;                  \
        p = __builtin_amdgcn_cvt_pk_f32_fp8((w).y, false);             \
        acc_agg[ks][4] += p.x; acc_agg[ks][5] += p.y;                  \
        p = __builtin_amdgcn_cvt_pk_f32_fp8((w).y, true);              \
        acc_agg[ks][6] += p.x; acc_agg[ks][7] += p.y;                  \
    } while (0)

    {
        const u8* hp = h8 + q * 8;
        const u16* cp = csr + s0;
        for (int j = 0; j < dmax; ++j) {
            if (j < deg) {
                int c = (int)cp[j];
                const u8* rp = hp + (c << 7);    // c * D
                uint2 w0 = *(const uint2*)(rp);
                uint2 w1 = *(const uint2*)(rp + 32);
                uint2 w2 = *(const uint2*)(rp + 64);
                uint2 w3 = *(const uint2*)(rp + 96);
                UNPACK_ADD(0, w0);
                UNPACK_ADD(1, w1);
                UNPACK_ADD(2, w2);
                UNPACK_ADD(3, w3);
            }
        }
    }
#undef UNPACK_ADD

    float inv = 1.f / fmaxf((float)deg, 1.f);
    f16x8 Aa[4];
#pragma unroll
    for (int ks = 0; ks < 4; ++ks)
#pragma unroll
        for (int u = 0; u < 8; ++u) Aa[ks][u] = (f16)(acc_agg[ks][u] * inv);

    // ---- phase 2: load x fragments (relu inline) ----
    f16x8 Ax[4];
    const f16* xrow = xb + (size_t)rclamp * D + q * 8;
#pragma unroll
    for (int ks = 0; ks < 4; ++ks) {
        f16x8 v = *(const f16x8*)(xrow + ks * 32);
        if (RELU_X) {
#pragma unroll
            for (int u = 0; u < 8; ++u) v[u] = (v[u] < (f16)0) ? (f16)0 : v[u];
        }
        Ax[ks] = v;
    }

    f32x4 acc[8];
#pragma unroll
    for (int nt = 0; nt < 8; ++nt) acc[nt] = (f32x4){0.f, 0.f, 0.f, 0.f};

    for (int p = 0; p < 2; ++p) {
        __syncthreads();
        // stage Wl/Wr K-half: 2 mats x 128 n x 8 chunks of 16B = 2048 chunks
#pragma unroll
        for (int it = 0; it < 8; ++it) {
            int idx = tid + it * 256;
            int mat = idx >> 10;
            int n   = (idx >> 3) & 127;
            int c   = idx & 7;
            const f16* W = mat ? Wr : Wl;
            f16x8 v = *(const f16x8*)(W + n * D + p * 64 + c * 8);
            *(f16x8*)&sW[mat][n][c * 8] = v;
        }
        __syncthreads();

#pragma unroll
        for (int nt = 0; nt < 8; ++nt) {
#pragma unroll
            for (int k2 = 0; k2 < 2; ++k2) {
                f16x8 bl = *(const f16x8*)&sW[0][nt * 16 + lm][k2 * 32 + q * 8];
                acc[nt] = __builtin_amdgcn_mfma_f32_16x16x32_f16(Aa[p * 2 + k2], bl, acc[nt], 0, 0, 0);
                f16x8 br = *(const f16x8*)&sW[1][nt * 16 + lm][k2 * 32 + q * 8];
                acc[nt] = __builtin_amdgcn_mfma_f32_16x16x32_f16(Ax[p * 2 + k2], br, acc[nt], 0, 0, 0);
            }
        }
    }

    // epilogue: bias (+ f16 residual from xb). In-place outh==xb is safe:
    // each (m,n) is read & written by exactly one lane, rows owned by this wave.
#pragma unroll
    for (int nt = 0; nt < 8; ++nt) {
        int n = nt * 16 + lm;
        float bval = bias[n];
#pragma unroll
        for (int r = 0; r < 4; ++r) {
            int m = mt + q * 4 + r;
            if (m < NN) {
                size_t idx = (size_t)m * D + n;
                float v = acc[nt][r] + bval;
                if (ADD_RES) v += (float)xb[idx];
                if (OUT_F32) {
                    outf[idx] = v;
                } else {
                    outh[idx] = (f16)v;
                    u32 t = __builtin_amdgcn_cvt_pk_fp8_f32(fmaxf(v, 0.f), 0.f, 0, false);
                    out8[idx] = (u8)(t & 0xffu);
                }
            }
        }
    }
}

// ---------------- launch ----------------

extern "C" void kernel_launch(void* const* d_in, const int* in_sizes, int n_in,
                              void* d_out, int out_size, void* d_ws, size_t ws_size,
                              hipStream_t stream) {
    const float* x    = (const float*)d_in[0];
    const int*   erow = (const int*)d_in[1];
    const int*   ecol = (const int*)d_in[2];
    const float* Wl0 = (const float*)d_in[3];
    const float* Wr0 = (const float*)d_in[4];
    const float* b0  = (const float*)d_in[5];
    const float* Wl1 = (const float*)d_in[6];
    const float* Wr1 = (const float*)d_in[7];
    const float* b1  = (const float*)d_in[8];
    const float* Wl2 = (const float*)d_in[9];
    const float* Wr2 = (const float*)d_in[10];
    const float* b2  = (const float*)d_in[11];

    char* ws = (char*)d_ws;
    size_t off = 0;
    auto carve = [&](size_t bytes) -> void* {
        void* p = ws + off;
        off = (off + bytes + 255) & ~(size_t)255;
        return p;
    };
    int*   deg     = (int*)carve((size_t)NN * 4);
    int*   offsets = (int*)carve((size_t)(NN + 1) * 4);
    int*   bsum    = (int*)carve(64 * 4);
    u16*   rank    = (u16*)carve((size_t)NE * 2);
    u16*   csr_col = (u16*)carve((size_t)NE * 2);
    f16*   xf      = (f16*)carve((size_t)NN * D * 2);
    f16*   x1      = (f16*)carve((size_t)NN * D * 2);
    u8*    xf8     = (u8*)carve((size_t)NN * D);
    u8*    x1f8    = (u8*)carve((size_t)NN * D);
    f16*   wl0 = (f16*)carve(D * D * 2); f16* wr0 = (f16*)carve(D * D * 2);
    f16*   wl1 = (f16*)carve(D * D * 2); f16* wr1 = (f16*)carve(D * D * 2);
    f16*   wl2 = (f16*)carve(D * D * 2); f16* wr2 = (f16*)carve(D * D * 2);
    (void)ws_size; (void)in_sizes; (void)n_in; (void)out_size;

    float* outp = (float*)d_out;

    // prep: converts + deg zero (6250 + 96 + 196 blocks)
    prep<<<6542, 256, 0, stream>>>(x, xf, xf8, Wl0, Wr0, Wl1, Wr1, Wl2, Wr2,
                                   wl0, wr0, wl1, wr1, wl2, wr2, deg);

    // CSR build
    count_deg_rank<<<(NE + 255) / 256, 256, 0, stream>>>(erow, deg, rank, NE);
    const int nsb = (NN + 1023) / 1024;   // 49
    scan_partial<<<nsb, 1024, 0, stream>>>(deg, bsum, NN);
    scan_final<<<nsb, 1024, 0, stream>>>(deg, bsum, offsets, NN, nsb);
    fill_csr<<<(NE + 255) / 256, 256, 0, stream>>>(erow, ecol, rank, offsets, csr_col, NE);

    const int ggrid = (NN + 63) / 64;       // 782

    // fp8 buffers ping-pong: xf8 -> x1f8 -> xf8 (gather input != fp8 output)
    // layer 0: x1 = agg(x)@Wl0^T + x@Wr0^T + b0; x1f8 = fp8(relu(x1))
    sage_fused_mfma<0, 0, 0><<<ggrid, 256, 0, stream>>>(
        xf8, offsets, csr_col, xf, wl0, wr0, b0, nullptr, x1, x1f8);
    // layer 1: x1 = agg(relu(x1))@Wl1^T + relu(x1)@Wr1^T + b1 + x1 (f16 in place)
    sage_fused_mfma<1, 1, 0><<<ggrid, 256, 0, stream>>>(
        x1f8, offsets, csr_col, x1, wl1, wr1, b1, nullptr, x1, xf8);
    // layer 2: out = agg(relu(x1))@Wl2^T + relu(x1)@Wr2^T + b2 + x1  (fp32)
    sage_fused_mfma<1, 1, 1><<<ggrid, 256, 0, stream>>>(
        xf8, offsets, csr_col, x1, wl2, wr2, b2, outp, nullptr, nullptr);
}